// Round 1
// baseline (994.440 us; speedup 1.0000x reference)
//
#include <hip/hip_runtime.h>

// Scene splat: out(C,H,W) zero-init, then add N patches (C,PH,PW) at
// per-patch (row, col) offsets. Overlaps accumulate -> atomicAdd (fp add is
// commutative; ordering diffs are far below the 0.186 absmax threshold).

constexpr int C  = 5;
constexpr int H  = 4096;
constexpr int W  = 4096;
constexpr int N  = 2000;
constexpr int PH = 64;
constexpr int PW = 64;

// Total float4 elements across all patches: N*C*PH*(PW/4) = 10,240,000
constexpr int TOTAL_F4 = N * C * PH * (PW / 4);

__global__ __launch_bounds__(256) void scene_splat(
    const float4* __restrict__ patches,   // (N, C, PH, PW) as float4s
    const int2*   __restrict__ positions, // (N, 2): .x = row off, .y = col off
    float*        __restrict__ out)       // (C, H, W)
{
    int f = blockIdx.x * blockDim.x + threadIdx.x;  // float4 index
    if (f >= TOTAL_F4) return;

    // f = ((n*C + c)*PH + ph)*(PW/4) + pw4  -- matches patch memory layout
    int pw4 = f & 15;          // PW/4 = 16
    int ph  = (f >> 4) & 63;   // PH = 64
    int nc  = f >> 10;         // / (PH * PW/4)
    int c   = nc % C;
    int n   = nc / C;

    int2 pos = positions[n];
    int y = pos.x + ph;          // pos[0] indexes H (rows)
    int x = pos.y + (pw4 << 2);  // pos[1] indexes W (cols)

    float4 v = patches[f];       // coalesced 16B load

    float* o = out + ((size_t)c * H + y) * (size_t)W + x;
    atomicAdd(o + 0, v.x);
    atomicAdd(o + 1, v.y);
    atomicAdd(o + 2, v.z);
    atomicAdd(o + 3, v.w);
}

extern "C" void kernel_launch(void* const* d_in, const int* in_sizes, int n_in,
                              void* d_out, int out_size, void* d_ws, size_t ws_size,
                              hipStream_t stream) {
    const float4* patches   = (const float4*)d_in[0];
    const int2*   positions = (const int2*)d_in[1];
    float*        out       = (float*)d_out;

    // Harness poisons d_out with 0xAA before every call -> zero it first.
    hipMemsetAsync(out, 0, (size_t)out_size * sizeof(float), stream);

    int threads = 256;
    int blocks  = (TOTAL_F4 + threads - 1) / threads;  // 40,000
    scene_splat<<<blocks, threads, 0, stream>>>(patches, positions, out);
}

// Round 2
// 519.679 us; speedup vs baseline: 1.9136x; 1.9136x over previous
//
#include <hip/hip_runtime.h>

// Scene splat, gather formulation.
// Round-1 lesson: 41M global fp32 atomics cap at ~65 Gops/s (633 us, 1.2 TB/s,
// VALUBusy 1%) -- per-op L2 RMW cost, not bandwidth. So invert to gather:
//   1) bin patches into 64x64 output tiles (<=2x2 tiles per patch),
//   2) one block per (tile, channel): accumulate covering patch fragments in
//      registers, write the finished tile once (replaces memset + atomics).

constexpr int C  = 5;
constexpr int H  = 4096;
constexpr int W  = 4096;
constexpr int N  = 2000;
constexpr int PH = 64;
constexpr int PW = 64;

constexpr int TILE   = 64;
constexpr int TX     = W / TILE;        // 64 tiles across
constexpr int TY     = H / TILE;        // 64 tiles down
constexpr int NTILES = TX * TY;         // 4096
constexpr int CAP    = 128;             // max patches listed per tile (mean ~2, Poisson tail << 128)

__global__ __launch_bounds__(256) void bin_patches(
    const int2* __restrict__ positions,
    int*        __restrict__ counts,    // [NTILES]
    int*        __restrict__ lists)     // [NTILES][CAP]
{
    int n = blockIdx.x * blockDim.x + threadIdx.x;
    if (n >= N) return;
    int2 p = positions[n];              // .x = row offset, .y = col offset
    int ty0 = p.x >> 6, ty1 = (p.x + PH - 1) >> 6;
    int tx0 = p.y >> 6, tx1 = (p.y + PW - 1) >> 6;
    for (int ty = ty0; ty <= ty1; ++ty)
        for (int tx = tx0; tx <= tx1; ++tx) {
            int tile = ty * TX + tx;
            int slot = atomicAdd(&counts[tile], 1);
            if (slot < CAP) lists[tile * CAP + slot] = n;
        }
}

__global__ __launch_bounds__(256) void gather_tiles(
    const float* __restrict__ patches,   // (N, C, PH, PW)
    const int2*  __restrict__ positions,
    const int*   __restrict__ counts,
    const int*   __restrict__ lists,
    float*       __restrict__ out)       // (C, H, W)
{
    int tile = blockIdx.x;               // 0..NTILES-1
    int c    = blockIdx.y;               // 0..C-1
    int ty = tile >> 6, tx = tile & (TX - 1);
    int y0 = ty << 6,  x0 = tx << 6;
    int t  = threadIdx.x;

    // Each thread owns 4 float4s of the 64x64 tile:
    //   f4 = t + 256*k  (k=0..3), row = f4>>4, col4 = f4&15
    float4 acc[4] = {};

    int cnt = counts[tile];
    if (cnt > CAP) cnt = CAP;

    for (int i = 0; i < cnt; ++i) {
        int n = lists[tile * CAP + i];
        int2 p = positions[n];
        const float* pb = patches + ((size_t)n * C + c) * (PH * PW);
        #pragma unroll
        for (int k = 0; k < 4; ++k) {
            int f4 = t + 256 * k;
            int yy = f4 >> 4;
            int xb = (f4 & 15) << 2;
            int py = y0 + yy - p.x;          // row inside the patch
            if (py < 0 || py >= PH) continue;
            const float* prow = pb + py * PW;
            #pragma unroll
            for (int j = 0; j < 4; ++j) {
                int px = x0 + xb + j - p.y;  // col inside the patch
                if (px >= 0 && px < PW)
                    (&acc[k].x)[j] += prow[px];
            }
        }
    }

    // Single coalesced float4 store per slot; zero tiles write zeros
    // (this replaces the full-frame memset).
    float4* o4 = (float4*)out;
    #pragma unroll
    for (int k = 0; k < 4; ++k) {
        int f4 = t + 256 * k;
        int yy = f4 >> 4;
        int x4 = f4 & 15;
        o4[((size_t)c * H + (y0 + yy)) * (W / 4) + (x0 >> 2) + x4] = acc[k];
    }
}

extern "C" void kernel_launch(void* const* d_in, const int* in_sizes, int n_in,
                              void* d_out, int out_size, void* d_ws, size_t ws_size,
                              hipStream_t stream) {
    const float* patches   = (const float*)d_in[0];
    const int2*  positions = (const int2*)d_in[1];
    float*       out       = (float*)d_out;

    int* counts = (int*)d_ws;                        // NTILES ints
    int* lists  = counts + NTILES;                   // NTILES*CAP ints (~2 MB)

    // d_ws is re-poisoned before every timed call -> zero the counters.
    hipMemsetAsync(counts, 0, NTILES * sizeof(int), stream);

    bin_patches<<<(N + 255) / 256, 256, 0, stream>>>(positions, counts, lists);

    dim3 grid(NTILES, C);
    gather_tiles<<<grid, 256, 0, stream>>>(patches, positions, counts, lists, out);
}

// Round 4
// 486.299 us; speedup vs baseline: 2.0449x; 1.0686x over previous
//
#include <hip/hip_runtime.h>
#include <cstring>

// Scene splat, gather formulation v2.1 (v2 + compile fix: clang vector type
// for __builtin_nontemporal_store, which rejects HIP_vector_type float4).
// R1: 41M global atomics cap at 65 Gops/s -> gather inversion (994->519 us).
// R2: dur_us = ~315 us harness poison/restore + ~200 us gather (ideal ~100).
// This round: cheaper inner loop -- packed (n,pos) bin entries, hoisted
// fragment-rect math, dwordx4 fast path w/ scalar edge fallback, nt stores.

typedef float vf4 __attribute__((ext_vector_type(4)));

constexpr int C  = 5;
constexpr int H  = 4096;
constexpr int W  = 4096;
constexpr int N  = 2000;
constexpr int PH = 64;
constexpr int PW = 64;

constexpr int TILE   = 64;
constexpr int TX     = W / TILE;        // 64
constexpr int TY     = H / TILE;        // 64
constexpr int NTILES = TX * TY;         // 4096
constexpr int CAP    = 128;             // mean ~2 entries/tile; tail << 128

__global__ __launch_bounds__(256) void bin_patches(
    const int2* __restrict__ positions,
    int*        __restrict__ counts,    // [NTILES]
    int2*       __restrict__ lists)     // [NTILES][CAP] : {n, (py<<16)|px}
{
    int n = blockIdx.x * blockDim.x + threadIdx.x;
    if (n >= N) return;
    int2 p = positions[n];              // .x = row offset, .y = col offset
    int packed = (p.x << 16) | p.y;     // both < 4096, fit 16b
    int ty0 = p.x >> 6, ty1 = (p.x + PH - 1) >> 6;
    int tx0 = p.y >> 6, tx1 = (p.y + PW - 1) >> 6;
    for (int ty = ty0; ty <= ty1; ++ty)
        for (int tx = tx0; tx <= tx1; ++tx) {
            int tile = ty * TX + tx;
            int slot = atomicAdd(&counts[tile], 1);
            if (slot < CAP) lists[tile * CAP + slot] = make_int2(n, packed);
        }
}

__global__ __launch_bounds__(256) void gather_tiles(
    const float* __restrict__ patches,   // (N, C, PH, PW)
    const int*   __restrict__ counts,
    const int2*  __restrict__ lists,
    float*       __restrict__ out)       // (C, H, W)
{
    int tile = blockIdx.x;
    int c    = blockIdx.y;
    int y0 = (tile >> 6) << 6;
    int x0 = (tile & (TX - 1)) << 6;
    int t  = threadIdx.x;
    int row4 = t >> 4;                   // 0..15; thread owns rows row4+16k
    int colb = (t & 15) << 2;            // first of 4 consecutive cols owned

    vf4 acc[4] = {};

    int cnt = counts[tile];
    if (cnt > CAP) cnt = CAP;
    const int2* lst = lists + (size_t)tile * CAP;

    for (int i = 0; i < cnt; ++i) {
        int2 e = lst[i];                 // e.x = n, e.y = (py<<16)|px
        int py = e.y >> 16;
        int px = e.y & 0xffff;
        const float* pb = patches + ((size_t)e.x * C + c) * (PH * PW);
        int ry  = y0 - py;               // patch row of tile row 0
        int rxb = x0 - px + colb;        // patch col of this thread's chunk

        bool xfull = (unsigned)rxb <= (unsigned)(PW - 4);
        #pragma unroll
        for (int k = 0; k < 4; ++k) {
            int pr = ry + row4 + 16 * k;
            if ((unsigned)pr >= (unsigned)PH) continue;
            const float* prow = pb + pr * PW;
            if (xfull) {
                // 4 consecutive dwords, 4B-aligned -> dwordx4
                vf4 v;
                __builtin_memcpy(&v, prow + rxb, sizeof(vf4));
                acc[k] += v;
            } else {
                #pragma unroll
                for (int j = 0; j < 4; ++j) {
                    int pxx = rxb + j;
                    if ((unsigned)pxx < (unsigned)PW)
                        acc[k][j] += prow[pxx];
                }
            }
        }
    }

    // Final tile writeback: streaming (nt) stores -- write-once data, keep L2
    // for patch reads. Zero tiles write zeros -> replaces full-frame memset.
    vf4* o4 = (vf4*)(out + ((size_t)c * H + y0) * W + x0);
    #pragma unroll
    for (int k = 0; k < 4; ++k) {
        int yy = row4 + 16 * k;
        __builtin_nontemporal_store(acc[k], o4 + ((size_t)yy * (W / 4)) + (colb >> 2));
    }
}

extern "C" void kernel_launch(void* const* d_in, const int* in_sizes, int n_in,
                              void* d_out, int out_size, void* d_ws, size_t ws_size,
                              hipStream_t stream) {
    const float* patches   = (const float*)d_in[0];
    const int2*  positions = (const int2*)d_in[1];
    float*       out       = (float*)d_out;

    int*  counts = (int*)d_ws;                       // NTILES ints
    int2* lists  = (int2*)(counts + NTILES);         // NTILES*CAP int2 (4 MB)

    (void)hipMemsetAsync(counts, 0, NTILES * sizeof(int), stream);

    bin_patches<<<(N + 255) / 256, 256, 0, stream>>>(positions, counts, lists);

    dim3 grid(NTILES, C);
    gather_tiles<<<grid, 256, 0, stream>>>(patches, counts, lists, out);
}

// Round 5
// 482.529 us; speedup vs baseline: 2.0609x; 1.0078x over previous
//
#include <hip/hip_runtime.h>
#include <cstring>

// Scene splat, gather formulation v3.
// R1: 41M global atomics cap at 65 Gops/s -> gather inversion (994->519 us).
// R2/R4: ~315 us of dur_us is harness poison/restore (fixed); gather ~165 us
//        vs ~95 us traffic floor. dwordx4 fast path: -33 us.
// R5: merge all 5 channels into ONE block per tile (was one block per
//     (tile,channel)): entry list decoded once not 5x, and each entry now
//     yields 20 independent dwordx4 loads/thread (5x MLP for latency hiding).
//     acc = 5 ch x 4 row-chunks x float4 = 80 VGPRs.

typedef float vf4 __attribute__((ext_vector_type(4)));

constexpr int C  = 5;
constexpr int H  = 4096;
constexpr int W  = 4096;
constexpr int N  = 2000;
constexpr int PH = 64;
constexpr int PW = 64;

constexpr int TILE   = 64;
constexpr int TX     = W / TILE;        // 64
constexpr int TY     = H / TILE;        // 64
constexpr int NTILES = TX * TY;         // 4096
constexpr int CAP    = 128;             // mean ~2 entries/tile; tail << 128

__global__ __launch_bounds__(256) void bin_patches(
    const int2* __restrict__ positions,
    int*        __restrict__ counts,    // [NTILES]
    int2*       __restrict__ lists)     // [NTILES][CAP] : {n, (py<<16)|px}
{
    int n = blockIdx.x * blockDim.x + threadIdx.x;
    if (n >= N) return;
    int2 p = positions[n];              // .x = row offset, .y = col offset
    int packed = (p.x << 16) | p.y;     // both < 4096, fit 16b
    int ty0 = p.x >> 6, ty1 = (p.x + PH - 1) >> 6;
    int tx0 = p.y >> 6, tx1 = (p.y + PW - 1) >> 6;
    for (int ty = ty0; ty <= ty1; ++ty)
        for (int tx = tx0; tx <= tx1; ++tx) {
            int tile = ty * TX + tx;
            int slot = atomicAdd(&counts[tile], 1);
            if (slot < CAP) lists[tile * CAP + slot] = make_int2(n, packed);
        }
}

__global__ __launch_bounds__(256) void gather_tiles(
    const float* __restrict__ patches,   // (N, C, PH, PW)
    const int*   __restrict__ counts,
    const int2*  __restrict__ lists,
    float*       __restrict__ out)       // (C, H, W)
{
    int tile = blockIdx.x;
    int y0 = (tile >> 6) << 6;
    int x0 = (tile & (TX - 1)) << 6;
    int t  = threadIdx.x;
    int row4 = t >> 4;                   // 0..15; thread owns rows row4+16k
    int colb = (t & 15) << 2;            // first of 4 consecutive cols owned

    vf4 acc[C][4] = {};                  // 80 VGPRs of accumulator

    int cnt = counts[tile];
    if (cnt > CAP) cnt = CAP;
    const int2* lst = lists + (size_t)tile * CAP;

    for (int i = 0; i < cnt; ++i) {
        int2 e = lst[i];                 // e.x = n, e.y = (py<<16)|px
        int py = e.y >> 16;
        int px = e.y & 0xffff;
        const float* pb = patches + (size_t)e.x * (C * PH * PW);
        int ry  = y0 - py;               // patch row of tile row 0
        int rxb = x0 - px + colb;        // patch col of this thread's chunk

        bool xfull = (unsigned)rxb <= (unsigned)(PW - 4);
        #pragma unroll
        for (int k = 0; k < 4; ++k) {
            int pr = ry + row4 + 16 * k;
            if ((unsigned)pr >= (unsigned)PH) continue;
            const float* prow = pb + pr * PW;
            if (xfull) {
                #pragma unroll
                for (int c = 0; c < C; ++c) {     // 5 independent dwordx4s
                    vf4 v;
                    __builtin_memcpy(&v, prow + c * (PH * PW) + rxb, sizeof(vf4));
                    acc[c][k] += v;
                }
            } else {
                #pragma unroll
                for (int j = 0; j < 4; ++j) {
                    int pxx = rxb + j;
                    if ((unsigned)pxx < (unsigned)PW) {
                        #pragma unroll
                        for (int c = 0; c < C; ++c)
                            acc[c][k][j] += prow[c * (PH * PW) + pxx];
                    }
                }
            }
        }
    }

    // Final writeback: streaming (nt) stores; zero tiles write zeros
    // (replaces the full-frame memset).
    #pragma unroll
    for (int c = 0; c < C; ++c) {
        vf4* o4 = (vf4*)(out + ((size_t)c * H + y0) * W + x0);
        #pragma unroll
        for (int k = 0; k < 4; ++k) {
            int yy = row4 + 16 * k;
            __builtin_nontemporal_store(acc[c][k],
                o4 + (size_t)yy * (W / 4) + (colb >> 2));
        }
    }
}

extern "C" void kernel_launch(void* const* d_in, const int* in_sizes, int n_in,
                              void* d_out, int out_size, void* d_ws, size_t ws_size,
                              hipStream_t stream) {
    const float* patches   = (const float*)d_in[0];
    const int2*  positions = (const int2*)d_in[1];
    float*       out       = (float*)d_out;

    int*  counts = (int*)d_ws;                       // NTILES ints
    int2* lists  = (int2*)(counts + NTILES);         // NTILES*CAP int2 (4 MB)

    (void)hipMemsetAsync(counts, 0, NTILES * sizeof(int), stream);

    bin_patches<<<(N + 255) / 256, 256, 0, stream>>>(positions, counts, lists);

    gather_tiles<<<NTILES, 256, 0, stream>>>(patches, counts, lists, out);
}

// Round 6
// 478.560 us; speedup vs baseline: 2.0780x; 1.0083x over previous
//
#include <hip/hip_runtime.h>
#include <cstring>

// Scene splat, gather formulation v4.
// R1: 41M global atomics cap at 65 Gops/s -> gather inversion (994->519 us).
// R2/R4: ~308 us of dur_us is harness poison/restore (fixed floor); gather
//        ~165 us vs ~90 us traffic floor. dwordx4 fast path helped (-33).
// R5: channel-merge (5x MLP) was NEUTRAL -> not latency-bound on reads.
// R6 A/B: nt stores -> PLAIN stores. Theory: harness poison/restore leaves
//   d_out + patches resident in the 256MB L3; plain stores terminate in
//   L2/L3 (lazy writeback after kernel end) while nt forces full HBM drain
//   inside the kernel. Single-variable change vs R5.

typedef float vf4 __attribute__((ext_vector_type(4)));

constexpr int C  = 5;
constexpr int H  = 4096;
constexpr int W  = 4096;
constexpr int N  = 2000;
constexpr int PH = 64;
constexpr int PW = 64;

constexpr int TILE   = 64;
constexpr int TX     = W / TILE;        // 64
constexpr int TY     = H / TILE;        // 64
constexpr int NTILES = TX * TY;         // 4096
constexpr int CAP    = 128;             // mean ~2 entries/tile; tail << 128

__global__ __launch_bounds__(256) void bin_patches(
    const int2* __restrict__ positions,
    int*        __restrict__ counts,    // [NTILES]
    int2*       __restrict__ lists)     // [NTILES][CAP] : {n, (py<<16)|px}
{
    int n = blockIdx.x * blockDim.x + threadIdx.x;
    if (n >= N) return;
    int2 p = positions[n];              // .x = row offset, .y = col offset
    int packed = (p.x << 16) | p.y;     // both < 4096, fit 16b
    int ty0 = p.x >> 6, ty1 = (p.x + PH - 1) >> 6;
    int tx0 = p.y >> 6, tx1 = (p.y + PW - 1) >> 6;
    for (int ty = ty0; ty <= ty1; ++ty)
        for (int tx = tx0; tx <= tx1; ++tx) {
            int tile = ty * TX + tx;
            int slot = atomicAdd(&counts[tile], 1);
            if (slot < CAP) lists[tile * CAP + slot] = make_int2(n, packed);
        }
}

__global__ __launch_bounds__(256) void gather_tiles(
    const float* __restrict__ patches,   // (N, C, PH, PW)
    const int*   __restrict__ counts,
    const int2*  __restrict__ lists,
    float*       __restrict__ out)       // (C, H, W)
{
    int tile = blockIdx.x;
    int y0 = (tile >> 6) << 6;
    int x0 = (tile & (TX - 1)) << 6;
    int t  = threadIdx.x;
    int row4 = t >> 4;                   // 0..15; thread owns rows row4+16k
    int colb = (t & 15) << 2;            // first of 4 consecutive cols owned

    vf4 acc[C][4] = {};                  // 80 VGPRs of accumulator

    int cnt = counts[tile];
    if (cnt > CAP) cnt = CAP;
    const int2* lst = lists + (size_t)tile * CAP;

    for (int i = 0; i < cnt; ++i) {
        int2 e = lst[i];                 // e.x = n, e.y = (py<<16)|px
        int py = e.y >> 16;
        int px = e.y & 0xffff;
        const float* pb = patches + (size_t)e.x * (C * PH * PW);
        int ry  = y0 - py;               // patch row of tile row 0
        int rxb = x0 - px + colb;        // patch col of this thread's chunk

        bool xfull = (unsigned)rxb <= (unsigned)(PW - 4);
        #pragma unroll
        for (int k = 0; k < 4; ++k) {
            int pr = ry + row4 + 16 * k;
            if ((unsigned)pr >= (unsigned)PH) continue;
            const float* prow = pb + pr * PW;
            if (xfull) {
                #pragma unroll
                for (int c = 0; c < C; ++c) {     // 5 independent dwordx4s
                    vf4 v;
                    __builtin_memcpy(&v, prow + c * (PH * PW) + rxb, sizeof(vf4));
                    acc[c][k] += v;
                }
            } else {
                #pragma unroll
                for (int j = 0; j < 4; ++j) {
                    int pxx = rxb + j;
                    if ((unsigned)pxx < (unsigned)PW) {
                        #pragma unroll
                        for (int c = 0; c < C; ++c)
                            acc[c][k][j] += prow[c * (PH * PW) + pxx];
                    }
                }
            }
        }
    }

    // Final writeback: PLAIN stores (A/B vs R5's nt). Writes may terminate in
    // L2/L3 and write back after kernel end; zero tiles write zeros
    // (replaces the full-frame memset).
    #pragma unroll
    for (int c = 0; c < C; ++c) {
        vf4* o4 = (vf4*)(out + ((size_t)c * H + y0) * W + x0);
        #pragma unroll
        for (int k = 0; k < 4; ++k) {
            int yy = row4 + 16 * k;
            o4[(size_t)yy * (W / 4) + (colb >> 2)] = acc[c][k];
        }
    }
}

extern "C" void kernel_launch(void* const* d_in, const int* in_sizes, int n_in,
                              void* d_out, int out_size, void* d_ws, size_t ws_size,
                              hipStream_t stream) {
    const float* patches   = (const float*)d_in[0];
    const int2*  positions = (const int2*)d_in[1];
    float*       out       = (float*)d_out;

    int*  counts = (int*)d_ws;                       // NTILES ints
    int2* lists  = (int2*)(counts + NTILES);         // NTILES*CAP int2 (4 MB)

    (void)hipMemsetAsync(counts, 0, NTILES * sizeof(int), stream);

    bin_patches<<<(N + 255) / 256, 256, 0, stream>>>(positions, counts, lists);

    gather_tiles<<<NTILES, 256, 0, stream>>>(patches, counts, lists, out);
}